// Round 8
// baseline (848.646 us; speedup 1.0000x reference)
//
#include <hip/hip_runtime.h>
#include <hip/hip_bf16.h>
#include <math.h>

#define N_NODES 50000
#define N_EDGES 250000
#define BB      128
#define DD      302
#define QQ      600
#define CC      2000
#define NEG_SLOPE 0.2f
#define GS      304        // padded row stride for G and P (16B-aligned rows)
#define KP      320        // padded K (10 x 32)
#define SA      40         // LDS k-stride in shorts (32 + 8 pad)
#define HSTEPS  5          // k-steps per staged half
#define KHALF   160        // K per staged half
#define PC      64         // nodes per pooling chunk

typedef __attribute__((ext_vector_type(8))) short short8;
typedef __attribute__((ext_vector_type(4))) float f32x4;

// ---------------------------------------------------------------- CSR build
__global__ void k_deg_init(int* deg, int* cursor) {
    int i = blockIdx.x * blockDim.x + threadIdx.x;
    if (i < N_NODES) { deg[i] = 1; cursor[i] = 0; }  // 1 = self loop
}

__global__ void k_histogram(const int* __restrict__ dst, int* deg) {
    int e = blockIdx.x * blockDim.x + threadIdx.x;
    if (e < N_EDGES) atomicAdd(&deg[dst[e]], 1);
}

__global__ void k_scan_block(const int* __restrict__ deg, int* offs, int* partials) {
    __shared__ int sh[256];
    int i = blockIdx.x * 256 + threadIdx.x;
    int v = (i < N_NODES) ? deg[i] : 0;
    sh[threadIdx.x] = v;
    __syncthreads();
    for (int d = 1; d < 256; d <<= 1) {
        int t = (threadIdx.x >= d) ? sh[threadIdx.x - d] : 0;
        __syncthreads();
        sh[threadIdx.x] += t;
        __syncthreads();
    }
    if (i < N_NODES) offs[i] = sh[threadIdx.x] - v;   // exclusive
    if (threadIdx.x == 255) partials[blockIdx.x] = sh[255];
}

__global__ void k_scan_partials(int* partials, int nb) {
    __shared__ int sh[256];
    int v = (threadIdx.x < nb) ? partials[threadIdx.x] : 0;
    sh[threadIdx.x] = v;
    __syncthreads();
    for (int d = 1; d < 256; d <<= 1) {
        int t = (threadIdx.x >= d) ? sh[threadIdx.x - d] : 0;
        __syncthreads();
        sh[threadIdx.x] += t;
        __syncthreads();
    }
    if (threadIdx.x < nb) partials[threadIdx.x] = sh[threadIdx.x] - v;  // exclusive
}

__global__ void k_scan_add(int* offs, const int* __restrict__ partials) {
    int i = blockIdx.x * 256 + threadIdx.x;
    if (i < N_NODES) offs[i] += partials[blockIdx.x];
}

__global__ void k_scatter(const int* __restrict__ src, const int* __restrict__ dst,
                          const int* __restrict__ offs, int* cursor, int* esrc) {
    int i = blockIdx.x * blockDim.x + threadIdx.x;
    if (i < N_EDGES) {
        int d = dst[i];
        int pos = offs[d] + atomicAdd(&cursor[d], 1);
        esrc[pos] = src[i];
    } else if (i < N_EDGES + N_NODES) {
        int n = i - N_EDGES;
        int pos = offs[n] + atomicAdd(&cursor[n], 1);
        esrc[pos] = n;   // self loop
    }
}

// ---------------------------------------------------------------- theta -> padded hi/lo bf16
__global__ void k_theta_prep(const float* __restrict__ theta,
                             unsigned short* __restrict__ thhi,
                             unsigned short* __restrict__ thlo) {
    int idx = blockIdx.x * 256 + threadIdx.x;
    if (idx >= KP * KP) return;
    int n = idx / KP, k = idx % KP;
    float v = (n < DD && k < DD) ? theta[n * DD + k] : 0.f;
    unsigned int u  = __float_as_uint(v);
    unsigned int uh = (u + 0x8000u) & 0xffff0000u;    // round-half-up bf16
    float hf = __uint_as_float(uh);
    float lo = v - hf;
    unsigned int ul = (__float_as_uint(lo) + 0x8000u) >> 16;
    thhi[idx] = (unsigned short)(uh >> 16);
    thlo[idx] = (unsigned short)ul;
}

// v_s = theta^T @ att_src, v_d = theta^T @ att_dst; appended as B rows DD, DD+1.
__global__ void k_attvec(const float* __restrict__ theta,
                         const float* __restrict__ att_src,
                         const float* __restrict__ att_dst,
                         unsigned short* __restrict__ thhi,
                         unsigned short* __restrict__ thlo) {
    int k = blockIdx.x * 256 + threadIdx.x;
    if (k >= DD) return;
    float vs = 0.f, vd = 0.f;
    for (int j = 0; j < DD; j++) {
        float t = theta[j * DD + k];      // coalesced over k
        vs += t * att_src[j];
        vd += t * att_dst[j];
    }
    unsigned int u, uh, ul;
    u  = __float_as_uint(vs);
    uh = (u + 0x8000u) & 0xffff0000u;
    ul = (__float_as_uint(vs - __uint_as_float(uh)) + 0x8000u) >> 16;
    thhi[(size_t)DD * KP + k] = (unsigned short)(uh >> 16);
    thlo[(size_t)DD * KP + k] = (unsigned short)ul;
    u  = __float_as_uint(vd);
    uh = (u + 0x8000u) & 0xffff0000u;
    ul = (__float_as_uint(vd - __uint_as_float(uh)) + 0x8000u) >> 16;
    thhi[(size_t)(DD + 1) * KP + k] = (unsigned short)(uh >> 16);
    thlo[(size_t)(DD + 1) * KP + k] = (unsigned short)ul;
}

// ---------------------------------------------------------------- split-bf16 MFMA GEMM
// Half-K LDS staging (50 KB), 3 barriers total, 5 barrier-free k-steps per half.
__global__ __launch_bounds__(256, 3) void k_mfma_gemm(const float* __restrict__ A, int lda,
                                                      const unsigned short* __restrict__ Bhg,
                                                      const unsigned short* __restrict__ Blg,
                                                      float* __restrict__ C,
                                                      float* __restrict__ a_s,
                                                      float* __restrict__ a_d, int M) {
    __shared__ short Ah[HSTEPS][64 * SA];
    __shared__ short Al[HSTEPS][64 * SA];

    const int tid   = threadIdx.x;
    const int m0    = blockIdx.x * 64;
    const int lane  = tid & 63;
    const int wave  = tid >> 6;         // 0..3
    const int q     = lane >> 4;        // 0..3
    const int mr    = lane & 15;
    const int nbase = wave * 80;

    f32x4 acc[4][5];
    #pragma unroll
    for (int i = 0; i < 4; i++)
        #pragma unroll
        for (int j = 0; j < 5; j++)
            acc[i][j] = (f32x4){0.f, 0.f, 0.f, 0.f};

    const int  srow  = tid >> 2;        // 0..63
    const int  schk  = tid & 3;         // 0..3
    const bool rowok = (m0 + srow) < M;
    const float* arow = A + (size_t)(m0 + srow) * lda;

    // stage one K-half (5 chunks of 32): issue all 10 global loads first,
    // then convert to hi/lo bf16 and write LDS.
    auto stage_half = [&](int kbase) {
        float f[HSTEPS][8];
        #pragma unroll
        for (int c = 0; c < HSTEPS; c++) {
            int k0c = kbase + c * 32 + schk * 8;
            if (lda == GS) {
                float4 v0 = {0.f,0.f,0.f,0.f}, v1 = {0.f,0.f,0.f,0.f};
                if (rowok && k0c < GS) {      // k>=GS would read past the row: zero-pad
                    v0 = *(const float4*)(arow + k0c);
                    v1 = *(const float4*)(arow + k0c + 4);
                }
                f[c][0]=v0.x; f[c][1]=v0.y; f[c][2]=v0.z; f[c][3]=v0.w;
                f[c][4]=v1.x; f[c][5]=v1.y; f[c][6]=v1.z; f[c][7]=v1.w;
            } else {
                #pragma unroll
                for (int p = 0; p < 4; p++) {
                    int k = k0c + p * 2;
                    float2 t = {0.f, 0.f};
                    if (rowok && k < DD) t = *(const float2*)(arow + k);  // DD even
                    f[c][p*2] = t.x; f[c][p*2+1] = t.y;
                }
            }
        }
        #pragma unroll
        for (int c = 0; c < HSTEPS; c++) {
            unsigned int hp[4], lp[4];
            #pragma unroll
            for (int p = 0; p < 4; p++) {
                float a = f[c][p*2], b = f[c][p*2+1];
                __hip_bfloat162 h2 = __float22bfloat162_rn(make_float2(a, b));
                unsigned int hu; __builtin_memcpy(&hu, &h2, 4);
                float ha = __uint_as_float(hu << 16);
                float hb = __uint_as_float(hu & 0xffff0000u);
                __hip_bfloat162 l2 = __float22bfloat162_rn(make_float2(a - ha, b - hb));
                unsigned int lu; __builtin_memcpy(&lu, &l2, 4);
                hp[p] = hu; lp[p] = lu;
            }
            *(uint4*)&Ah[c][srow * SA + schk * 8] = (uint4){hp[0], hp[1], hp[2], hp[3]};
            *(uint4*)&Al[c][srow * SA + schk * 8] = (uint4){lp[0], lp[1], lp[2], lp[3]};
        }
    };

    // 5 k-steps over the staged half; no barriers inside.
    auto compute_half = [&](int kbase) {
        #pragma unroll
        for (int c = 0; c < HSTEPS; c++) {
            const int gk0 = kbase + c * 32;
            short8 bh[5], bl[5];
            #pragma unroll
            for (int nt = 0; nt < 5; nt++) {
                size_t boff = (size_t)(nbase + nt * 16 + mr) * KP + gk0 + q * 8;
                bh[nt] = *(const short8*)(Bhg + boff);
                bl[nt] = *(const short8*)(Blg + boff);
            }
            short8 ah[4], al[4];
            #pragma unroll
            for (int mt = 0; mt < 4; mt++) {
                ah[mt] = *(const short8*)&Ah[c][(mt * 16 + mr) * SA + q * 8];
                al[mt] = *(const short8*)&Al[c][(mt * 16 + mr) * SA + q * 8];
            }
            #pragma unroll
            for (int mt = 0; mt < 4; mt++)
                #pragma unroll
                for (int nt = 0; nt < 5; nt++) {
                    acc[mt][nt] = __builtin_amdgcn_mfma_f32_16x16x32_bf16(ah[mt], bh[nt], acc[mt][nt], 0, 0, 0);
                    acc[mt][nt] = __builtin_amdgcn_mfma_f32_16x16x32_bf16(ah[mt], bl[nt], acc[mt][nt], 0, 0, 0);
                    acc[mt][nt] = __builtin_amdgcn_mfma_f32_16x16x32_bf16(al[mt], bh[nt], acc[mt][nt], 0, 0, 0);
                }
        }
    };

    stage_half(0);
    __syncthreads();
    compute_half(0);
    __syncthreads();          // all waves done reading half 0
    stage_half(KHALF);
    __syncthreads();
    compute_half(KHALF);

    // epilogue: C/D layout col=lane&15, row=(lane>>4)*4+reg
    #pragma unroll
    for (int mt = 0; mt < 4; mt++) {
        int row_b = m0 + mt * 16 + q * 4;
        #pragma unroll
        for (int nt = 0; nt < 5; nt++) {
            int col = nbase + nt * 16 + mr;
            if (col > DD + 1) continue;
            #pragma unroll
            for (int r = 0; r < 4; r++) {
                int row = row_b + r;
                if (row >= M) continue;
                float v = acc[mt][nt][r];
                if (col < DD)            C[(size_t)row * GS + col] = v;
                else if (col == DD)      a_s[row] = v;
                else                     a_d[row] = v;
            }
        }
    }
}

// ---------------------------------------------------------------- tiled SGEMM (final linear)
#define BM 64
#define BN 64
#define BK 16
__global__ __launch_bounds__(256) void k_gemm_nt(const float* __restrict__ A,
                                                 const float* __restrict__ B,
                                                 float* __restrict__ C,
                                                 int M, int N, int K,
                                                 const float* __restrict__ bias) {
    __shared__ float As[BK][BM + 4];
    __shared__ float Bs[BK][BN + 4];
    int m0 = blockIdx.y * BM;
    int n0 = blockIdx.x * BN;
    int tid = threadIdx.x;
    int tr = tid >> 4;
    int tc = tid & 15;
    float acc[4][4] = {};
    for (int k0 = 0; k0 < K; k0 += BK) {
        #pragma unroll
        for (int j = 0; j < 4; j++) {
            int e = tid + 256 * j;
            int r = e >> 4;
            int k = e & 15;
            int gk = k0 + k;
            int gm = m0 + r;
            float va = 0.f;
            if (gm < M && gk < K) va = A[(size_t)gm * K + gk];
            As[k][r] = va;
            int gn = n0 + r;
            float vb = 0.f;
            if (gn < N && gk < K) vb = B[(size_t)gn * K + gk];
            Bs[k][r] = vb;
        }
        __syncthreads();
        #pragma unroll
        for (int k = 0; k < BK; k++) {
            float a[4], b[4];
            #pragma unroll
            for (int i = 0; i < 4; i++) a[i] = As[k][tr * 4 + i];
            #pragma unroll
            for (int j = 0; j < 4; j++) b[j] = Bs[k][tc * 4 + j];
            #pragma unroll
            for (int i = 0; i < 4; i++)
                #pragma unroll
                for (int j = 0; j < 4; j++)
                    acc[i][j] += a[i] * b[j];
        }
        __syncthreads();
    }
    #pragma unroll
    for (int i = 0; i < 4; i++) {
        int gm = m0 + tr * 4 + i;
        if (gm >= M) continue;
        #pragma unroll
        for (int j = 0; j < 4; j++) {
            int gn = n0 + tc * 4 + j;
            if (gn < N) {
                float v = acc[i][j];
                if (bias) v += bias[gn];
                C[(size_t)gm * N + gn] = v;
            }
        }
    }
}

// ---------------------------------------------------------------- qp = query @ attW  (thread/output)
__global__ __launch_bounds__(256) void k_qp(const float* __restrict__ query,
                                            const float* __restrict__ attW,
                                            float* __restrict__ qp) {
    int b = blockIdx.y;
    int d = blockIdx.x * 256 + threadIdx.x;
    if (d >= DD) return;
    const float* qrow = query + (size_t)b * QQ;
    float acc = 0.f;
    #pragma unroll 8
    for (int q = 0; q < QQ; q++) acc += qrow[q] * attW[(size_t)q * DD + d];
    qp[(size_t)b * DD + d] = acc;
}

// ---------------------------------------------------------------- softmax-aggregate (wave / dst node)
__global__ __launch_bounds__(256) void k_aggregate(const float* __restrict__ h, int ld,
                                                   const float* __restrict__ a_s,
                                                   const float* __restrict__ a_d,
                                                   const int* __restrict__ offs,
                                                   const int* __restrict__ deg,
                                                   const int* __restrict__ esrc,
                                                   const float* __restrict__ bias,
                                                   float* __restrict__ out) {
    int gid = blockIdx.x * blockDim.x + threadIdx.x;
    int n = gid >> 6, lane = gid & 63;
    if (n >= N_NODES) return;
    int beg = offs[n], cnt = deg[n];
    float adn = a_d[n];
    float m = -INFINITY;
    for (int i = lane; i < cnt; i += 64) {
        float e = a_s[esrc[beg + i]] + adn;
        e = (e > 0.f) ? e : NEG_SLOPE * e;
        m = fmaxf(m, e);
    }
    for (int off = 32; off; off >>= 1) m = fmaxf(m, __shfl_xor(m, off));
    float den = 0.f;
    for (int i = lane; i < cnt; i += 64) {
        float e = a_s[esrc[beg + i]] + adn;
        e = (e > 0.f) ? e : NEG_SLOPE * e;
        den += __expf(e - m);
    }
    for (int off = 32; off; off >>= 1) den += __shfl_xor(den, off);
    float inv_den = 1.f / den;
    float acc[5] = {0.f, 0.f, 0.f, 0.f, 0.f};
    for (int i = 0; i < cnt; i++) {
        int s = esrc[beg + i];
        float e = a_s[s] + adn;
        e = (e > 0.f) ? e : NEG_SLOPE * e;
        float w = __expf(e - m) * inv_den;
        const float* row = h + (size_t)s * ld;
        #pragma unroll
        for (int j = 0; j < 5; j++) {
            int f = lane + 64 * j;
            if (f < DD) acc[j] += w * row[f];
        }
    }
    #pragma unroll
    for (int j = 0; j < 5; j++) {
        int f = lane + 64 * j;
        if (f < DD) {
            float v = acc[j] + bias[f];
            out[(size_t)n * ld + f] = fmaxf(v, 0.f);
        }
    }
    if (lane < GS - DD) out[(size_t)n * ld + DD + lane] = 0.f;  // zero pad cols
}

// ---------------------------------------------------------------- pooling pieces
// batch is SORTED -> per-graph bounds via binary search (no atomics).
__global__ void k_gbounds(const int* __restrict__ batch, int* goffs, int* gcnt) {
    __shared__ int bound[BB + 1];
    int b = threadIdx.x;
    if (b <= BB) {
        int lo = 0, hi = N_NODES;
        while (lo < hi) {                 // first i with batch[i] >= b
            int mid = (lo + hi) >> 1;
            if (batch[mid] < b) lo = mid + 1; else hi = mid;
        }
        bound[b] = lo;
    }
    __syncthreads();
    if (b < BB) {
        goffs[b] = bound[b];
        gcnt[b]  = bound[b + 1] - bound[b];
    }
}

__global__ void k_scores(const float* __restrict__ h, int ld,
                         const float* __restrict__ qp,
                         const int* __restrict__ batch, float* sarr) {
    int gid = blockIdx.x * blockDim.x + threadIdx.x;
    int n = gid >> 6, lane = gid & 63;
    if (n >= N_NODES) return;
    const float* row = h + (size_t)n * ld;
    const float* q = qp + (size_t)batch[n] * DD;
    float acc = 0.f;
    for (int j = lane; j < DD; j += 64) acc += row[j] * q[j];
    for (int off = 32; off; off >>= 1) acc += __shfl_down(acc, off);
    if (lane == 0) sarr[n] = acc * 0.04082482904638630f;   // 1/sqrt(600)
}

// per-graph softmax stats over sarr
__global__ __launch_bounds__(256) void k_gstats(const float* __restrict__ sarr,
                                                const int* __restrict__ goffs,
                                                const int* __restrict__ gcnt,
                                                float* __restrict__ gm,
                                                float* __restrict__ gdeninv) {
    int b = blockIdx.x;
    int beg = goffs[b], cnt = gcnt[b];
    __shared__ float red[256];
    float m = -INFINITY;
    for (int i = threadIdx.x; i < cnt; i += 256) m = fmaxf(m, sarr[beg + i]);
    red[threadIdx.x] = m;
    __syncthreads();
    for (int d = 128; d; d >>= 1) {
        if (threadIdx.x < d) red[threadIdx.x] = fmaxf(red[threadIdx.x], red[threadIdx.x + d]);
        __syncthreads();
    }
    m = red[0];
    __syncthreads();
    float den = 0.f;
    for (int i = threadIdx.x; i < cnt; i += 256) den += __expf(sarr[beg + i] - m);
    red[threadIdx.x] = den;
    __syncthreads();
    for (int d = 128; d; d >>= 1) {
        if (threadIdx.x < d) red[threadIdx.x] += red[threadIdx.x + d];
        __syncthreads();
    }
    if (threadIdx.x == 0) {
        gm[b] = m;
        gdeninv[b] = (cnt > 0) ? 1.f / red[0] : 0.f;
    }
}

__global__ void k_wn(const float* __restrict__ sarr, const int* __restrict__ batch,
                     const float* __restrict__ gm, const float* __restrict__ gdeninv,
                     float* __restrict__ wn) {
    int n = blockIdx.x * 256 + threadIdx.x;
    if (n >= N_NODES) return;
    int b = batch[n];
    wn[n] = __expf(sarr[n] - gm[b]) * gdeninv[b];
}

__global__ void k_pzero(float* pooled) {
    int i = blockIdx.x * 256 + threadIdx.x;
    if (i < BB * DD) pooled[i] = 0.f;
}

// node-chunk-parallel weighted segment sum (batch sorted; flush at graph boundaries)
__global__ __launch_bounds__(256) void k_poolacc(const float* __restrict__ h, int ld,
                                                 const float* __restrict__ wn,
                                                 const int* __restrict__ batch,
                                                 float* __restrict__ pooled) {
    int c0 = blockIdx.x * PC;
    if (c0 >= N_NODES) return;
    int nmax = N_NODES - c0; if (nmax > PC) nmax = PC;
    __shared__ int   sb[PC];
    __shared__ float sw[PC];
    for (int i = threadIdx.x; i < nmax; i += 256) {
        sb[i] = batch[c0 + i];
        sw[i] = wn[c0 + i];
    }
    __syncthreads();
    int f0 = threadIdx.x, f1 = threadIdx.x + 256;
    float a0 = 0.f, a1 = 0.f;
    int g = sb[0];
    for (int i = 0; i < nmax; i++) {
        int bi = sb[i];
        if (bi != g) {                       // wave-uniform branch
            if (f0 < DD) atomicAdd(&pooled[(size_t)g * DD + f0], a0);
            if (f1 < DD) atomicAdd(&pooled[(size_t)g * DD + f1], a1);
            a0 = 0.f; a1 = 0.f; g = bi;
        }
        float w = sw[i];
        const float* row = h + (size_t)(c0 + i) * ld;
        if (f0 < DD) a0 += w * row[f0];
        if (f1 < DD) a1 += w * row[f1];
    }
    if (f0 < DD) atomicAdd(&pooled[(size_t)g * DD + f0], a0);
    if (f1 < DD) atomicAdd(&pooled[(size_t)g * DD + f1], a1);
}

__global__ void k_prelu(const float* __restrict__ pooled, float* __restrict__ pr) {
    int i = blockIdx.x * 256 + threadIdx.x;
    if (i < BB * DD) pr[i] = fmaxf(pooled[i], 0.f);
}

// ---------------------------------------------------------------- launch
extern "C" void kernel_launch(void* const* d_in, const int* in_sizes, int n_in,
                              void* d_out, int out_size, void* d_ws, size_t ws_size,
                              hipStream_t stream) {
    const float* x        = (const float*)d_in[0];
    const int*   edges    = (const int*)d_in[1];   // [2, E]
    const float* query    = (const float*)d_in[2];
    const int*   batch    = (const int*)d_in[3];
    const float* theta    = (const float*)d_in[4];
    const float* att_src  = (const float*)d_in[5];
    const float* att_dst  = (const float*)d_in[6];
    const float* gat_bias = (const float*)d_in[7];
    const float* attW     = (const float*)d_in[8];
    const float* lin_w    = (const float*)d_in[9];
    const float* lin_b    = (const float*)d_in[10];
    float* out = (float*)d_out;

    char* ws = (char*)d_ws;
    size_t off = 0;
    auto alloc = [&](size_t bytes) -> void* {
        off = (off + 255) & ~(size_t)255;
        void* p = ws + off;
        off += bytes;
        return p;
    };

    float* G    = (float*)alloc((size_t)N_NODES * GS * 4);   // gemm output (padded stride)
    float* P    = (float*)alloc((size_t)N_NODES * GS * 4);   // layer output (padded stride)
    unsigned short* thhi = (unsigned short*)alloc((size_t)KP * KP * 2);
    unsigned short* thlo = (unsigned short*)alloc((size_t)KP * KP * 2);
    float* a_s  = (float*)alloc((size_t)N_NODES * 4);
    float* a_d  = (float*)alloc((size_t)N_NODES * 4);
    float* sarr = (float*)alloc((size_t)N_NODES * 4);
    float* wn   = (float*)alloc((size_t)N_NODES * 4);
    int* deg    = (int*)alloc((size_t)N_NODES * 4);
    int* cursor = (int*)alloc((size_t)N_NODES * 4);
    int* offs   = (int*)alloc((size_t)N_NODES * 4);
    int* esrc   = (int*)alloc((size_t)(N_EDGES + N_NODES) * 4);
    int* partials = (int*)alloc(256 * 4);
    int* gcnt   = (int*)alloc(BB * 4);
    int* goffs  = (int*)alloc(BB * 4);
    float* gm   = (float*)alloc(BB * 4);
    float* gdi  = (float*)alloc(BB * 4);
    float* qp   = (float*)alloc((size_t)BB * DD * 4);
    float* pooled = (float*)alloc((size_t)BB * DD * 4);
    float* pr   = (float*)alloc((size_t)BB * DD * 4);

    const int* e_src = edges;
    const int* e_dst = edges + N_EDGES;

    const int NB_SCAN = (N_NODES + 255) / 256;   // 196

    // ---- CSR build
    k_deg_init<<<NB_SCAN, 256, 0, stream>>>(deg, cursor);
    k_histogram<<<(N_EDGES + 255) / 256, 256, 0, stream>>>(e_dst, deg);
    k_scan_block<<<NB_SCAN, 256, 0, stream>>>(deg, offs, partials);
    k_scan_partials<<<1, 256, 0, stream>>>(partials, NB_SCAN);
    k_scan_add<<<NB_SCAN, 256, 0, stream>>>(offs, partials);
    k_scatter<<<(N_EDGES + N_NODES + 255) / 256, 256, 0, stream>>>(e_src, e_dst, offs, cursor, esrc);

    // ---- theta hi/lo split + attention-vector rows (once; shared across layers)
    k_theta_prep<<<(KP * KP + 255) / 256, 256, 0, stream>>>(theta, thhi, thlo);
    k_attvec<<<(DD + 255) / 256, 256, 0, stream>>>(theta, att_src, att_dst, thhi, thlo);

    // ---- 3 GAT layers
    int mfma_blocks = (N_NODES + 63) / 64;   // 782
    int wave_blocks = (N_NODES + 3) / 4;
    const float* cur = x;
    int cur_ld = DD;
    for (int layer = 0; layer < 3; layer++) {
        k_mfma_gemm<<<mfma_blocks, 256, 0, stream>>>(cur, cur_ld, thhi, thlo, G, a_s, a_d, N_NODES);
        k_aggregate<<<wave_blocks, 256, 0, stream>>>(G, GS, a_s, a_d, offs, deg, esrc, gat_bias, P);
        cur = P;
        cur_ld = GS;
    }

    // ---- attention pooling + classifier
    {
        dim3 g((DD + 255) / 256, BB);
        k_qp<<<g, 256, 0, stream>>>(query, attW, qp);
    }
    k_gbounds<<<1, 256, 0, stream>>>(batch, goffs, gcnt);
    k_scores<<<wave_blocks, 256, 0, stream>>>(P, GS, qp, batch, sarr);
    k_gstats<<<BB, 256, 0, stream>>>(sarr, goffs, gcnt, gm, gdi);
    k_wn<<<NB_SCAN, 256, 0, stream>>>(sarr, batch, gm, gdi, wn);
    k_pzero<<<(BB * DD + 255) / 256, 256, 0, stream>>>(pooled);
    k_poolacc<<<(N_NODES + PC - 1) / PC, 256, 0, stream>>>(P, GS, wn, batch, pooled);
    k_prelu<<<(BB * DD + 255) / 256, 256, 0, stream>>>(pooled, pr);
    {
        dim3 g((CC + BN - 1) / BN, (BB + BM - 1) / BM);
        k_gemm_nt<<<g, 256, 0, stream>>>(pr, lin_w, out, BB, CC, DD, lin_b);
    }
}

// Round 9
// 814.325 us; speedup vs baseline: 1.0421x; 1.0421x over previous
//
#include <hip/hip_runtime.h>
#include <hip/hip_bf16.h>
#include <math.h>

#define N_NODES 50000
#define N_EDGES 250000
#define BB      128
#define DD      302
#define QQ      600
#define CC      2000
#define NEG_SLOPE 0.2f
#define GS      304        // padded row stride for G and P (16B-aligned rows)
#define KP      320        // padded K (10 x 32)
#define SA      40         // LDS k-stride in shorts (32 + 8 pad)
#define KSTEPS  10         // KP / 32
#define PC      64         // nodes per pooling chunk

typedef __attribute__((ext_vector_type(8))) short short8;
typedef __attribute__((ext_vector_type(4))) float f32x4;

// ---------------------------------------------------------------- CSR build
__global__ void k_deg_init(int* deg, int* cursor) {
    int i = blockIdx.x * blockDim.x + threadIdx.x;
    if (i < N_NODES) { deg[i] = 1; cursor[i] = 0; }  // 1 = self loop
}

__global__ void k_histogram(const int* __restrict__ dst, int* deg) {
    int e = blockIdx.x * blockDim.x + threadIdx.x;
    if (e < N_EDGES) atomicAdd(&deg[dst[e]], 1);
}

__global__ void k_scan_block(const int* __restrict__ deg, int* offs, int* partials) {
    __shared__ int sh[256];
    int i = blockIdx.x * 256 + threadIdx.x;
    int v = (i < N_NODES) ? deg[i] : 0;
    sh[threadIdx.x] = v;
    __syncthreads();
    for (int d = 1; d < 256; d <<= 1) {
        int t = (threadIdx.x >= d) ? sh[threadIdx.x - d] : 0;
        __syncthreads();
        sh[threadIdx.x] += t;
        __syncthreads();
    }
    if (i < N_NODES) offs[i] = sh[threadIdx.x] - v;   // exclusive
    if (threadIdx.x == 255) partials[blockIdx.x] = sh[255];
}

__global__ void k_scan_partials(int* partials, int nb) {
    __shared__ int sh[256];
    int v = (threadIdx.x < nb) ? partials[threadIdx.x] : 0;
    sh[threadIdx.x] = v;
    __syncthreads();
    for (int d = 1; d < 256; d <<= 1) {
        int t = (threadIdx.x >= d) ? sh[threadIdx.x - d] : 0;
        __syncthreads();
        sh[threadIdx.x] += t;
        __syncthreads();
    }
    if (threadIdx.x < nb) partials[threadIdx.x] = sh[threadIdx.x] - v;  // exclusive
}

__global__ void k_scan_add(int* offs, const int* __restrict__ partials) {
    int i = blockIdx.x * 256 + threadIdx.x;
    if (i < N_NODES) offs[i] += partials[blockIdx.x];
}

__global__ void k_scatter(const int* __restrict__ src, const int* __restrict__ dst,
                          const int* __restrict__ offs, int* cursor, int* esrc) {
    int i = blockIdx.x * blockDim.x + threadIdx.x;
    if (i < N_EDGES) {
        int d = dst[i];
        int pos = offs[d] + atomicAdd(&cursor[d], 1);
        esrc[pos] = src[i];
    } else if (i < N_EDGES + N_NODES) {
        int n = i - N_EDGES;
        int pos = offs[n] + atomicAdd(&cursor[n], 1);
        esrc[pos] = n;   // self loop
    }
}

// ---------------------------------------------------------------- theta -> padded hi/lo bf16
__global__ void k_theta_prep(const float* __restrict__ theta,
                             unsigned short* __restrict__ thhi,
                             unsigned short* __restrict__ thlo) {
    int idx = blockIdx.x * 256 + threadIdx.x;
    if (idx >= KP * KP) return;
    int n = idx / KP, k = idx % KP;
    float v = (n < DD && k < DD) ? theta[n * DD + k] : 0.f;
    unsigned int u  = __float_as_uint(v);
    unsigned int uh = (u + 0x8000u) & 0xffff0000u;    // round-half-up bf16
    float hf = __uint_as_float(uh);
    float lo = v - hf;
    unsigned int ul = (__float_as_uint(lo) + 0x8000u) >> 16;
    thhi[idx] = (unsigned short)(uh >> 16);
    thlo[idx] = (unsigned short)ul;
}

// v_s = theta^T @ att_src, v_d = theta^T @ att_dst; appended as B rows DD, DD+1.
__global__ void k_attvec(const float* __restrict__ theta,
                         const float* __restrict__ att_src,
                         const float* __restrict__ att_dst,
                         unsigned short* __restrict__ thhi,
                         unsigned short* __restrict__ thlo) {
    int k = blockIdx.x * 256 + threadIdx.x;
    if (k >= DD) return;
    float vs = 0.f, vd = 0.f;
    for (int j = 0; j < DD; j++) {
        float t = theta[j * DD + k];      // coalesced over k
        vs += t * att_src[j];
        vd += t * att_dst[j];
    }
    unsigned int u, uh, ul;
    u  = __float_as_uint(vs);
    uh = (u + 0x8000u) & 0xffff0000u;
    ul = (__float_as_uint(vs - __uint_as_float(uh)) + 0x8000u) >> 16;
    thhi[(size_t)DD * KP + k] = (unsigned short)(uh >> 16);
    thlo[(size_t)DD * KP + k] = (unsigned short)ul;
    u  = __float_as_uint(vd);
    uh = (u + 0x8000u) & 0xffff0000u;
    ul = (__float_as_uint(vd - __uint_as_float(uh)) + 0x8000u) >> 16;
    thhi[(size_t)(DD + 1) * KP + k] = (unsigned short)(uh >> 16);
    thlo[(size_t)(DD + 1) * KP + k] = (unsigned short)ul;
}

// ---------------------------------------------------------------- split-bf16 MFMA GEMM
// Triple-buffered LDS (30 KB), prefetch distance 2 (16 staging floats in regs),
// one barrier per k-step. A-loads stay ~2 compute-steps in flight -> HBM latency hidden.
__global__ __launch_bounds__(256) void k_mfma_gemm(const float* __restrict__ A, int lda,
                                                   const unsigned short* __restrict__ Bhg,
                                                   const unsigned short* __restrict__ Blg,
                                                   float* __restrict__ C,
                                                   float* __restrict__ a_s,
                                                   float* __restrict__ a_d, int M) {
    __shared__ short Ah[3][64 * SA];
    __shared__ short Al[3][64 * SA];

    const int tid   = threadIdx.x;
    const int m0    = blockIdx.x * 64;
    const int lane  = tid & 63;
    const int wave  = tid >> 6;         // 0..3
    const int q     = lane >> 4;        // 0..3
    const int mr    = lane & 15;
    const int nbase = wave * 80;

    f32x4 acc[4][5];
    #pragma unroll
    for (int i = 0; i < 4; i++)
        #pragma unroll
        for (int j = 0; j < 5; j++)
            acc[i][j] = (f32x4){0.f, 0.f, 0.f, 0.f};

    const int  srow  = tid >> 2;        // 0..63
    const int  schk  = tid & 3;         // 0..3
    const bool rowok = (m0 + srow) < M;
    const float* arow = A + (size_t)(m0 + srow) * lda;

    float fa[2][8];

    auto load_stage = [&](float (&f)[8], int kbase) {
        int k0c = kbase + schk * 8;
        if (lda == GS) {
            float4 v0 = {0.f,0.f,0.f,0.f}, v1 = {0.f,0.f,0.f,0.f};
            if (rowok && k0c < GS) {          // k>=GS would read past the row: zero-pad
                v0 = *(const float4*)(arow + k0c);
                v1 = *(const float4*)(arow + k0c + 4);
            }
            f[0]=v0.x; f[1]=v0.y; f[2]=v0.z; f[3]=v0.w;
            f[4]=v1.x; f[5]=v1.y; f[6]=v1.z; f[7]=v1.w;
        } else {
            #pragma unroll
            for (int p = 0; p < 4; p++) {
                int k = k0c + p * 2;
                float2 t = {0.f, 0.f};
                if (rowok && k < DD) t = *(const float2*)(arow + k);  // DD even
                f[p*2] = t.x; f[p*2+1] = t.y;
            }
        }
    };

    auto write_stage = [&](int buf, float (&f)[8]) {
        unsigned int hp[4], lp[4];
        #pragma unroll
        for (int p = 0; p < 4; p++) {
            float a = f[p*2], b = f[p*2+1];
            __hip_bfloat162 h2 = __float22bfloat162_rn(make_float2(a, b));
            unsigned int hu; __builtin_memcpy(&hu, &h2, 4);
            float ha = __uint_as_float(hu << 16);
            float hb = __uint_as_float(hu & 0xffff0000u);
            __hip_bfloat162 l2 = __float22bfloat162_rn(make_float2(a - ha, b - hb));
            unsigned int lu; __builtin_memcpy(&lu, &l2, 4);
            hp[p] = hu; lp[p] = lu;
        }
        *(uint4*)&Ah[buf][srow * SA + schk * 8] = (uint4){hp[0], hp[1], hp[2], hp[3]};
        *(uint4*)&Al[buf][srow * SA + schk * 8] = (uint4){lp[0], lp[1], lp[2], lp[3]};
    };

    auto compute_step = [&](int buf, int gk0) {
        short8 bh[5], bl[5];
        #pragma unroll
        for (int nt = 0; nt < 5; nt++) {
            size_t boff = (size_t)(nbase + nt * 16 + mr) * KP + gk0 + q * 8;
            bh[nt] = *(const short8*)(Bhg + boff);
            bl[nt] = *(const short8*)(Blg + boff);
        }
        short8 ah[4], al[4];
        #pragma unroll
        for (int mt = 0; mt < 4; mt++) {
            ah[mt] = *(const short8*)&Ah[buf][(mt * 16 + mr) * SA + q * 8];
            al[mt] = *(const short8*)&Al[buf][(mt * 16 + mr) * SA + q * 8];
        }
        #pragma unroll
        for (int mt = 0; mt < 4; mt++)
            #pragma unroll
            for (int nt = 0; nt < 5; nt++) {
                acc[mt][nt] = __builtin_amdgcn_mfma_f32_16x16x32_bf16(ah[mt], bh[nt], acc[mt][nt], 0, 0, 0);
                acc[mt][nt] = __builtin_amdgcn_mfma_f32_16x16x32_bf16(ah[mt], bl[nt], acc[mt][nt], 0, 0, 0);
                acc[mt][nt] = __builtin_amdgcn_mfma_f32_16x16x32_bf16(al[mt], bh[nt], acc[mt][nt], 0, 0, 0);
            }
    };

    // prologue: k0 and k1 in flight; buf0 <- k0
    load_stage(fa[0], 0);
    load_stage(fa[1], 32);
    write_stage(0, fa[0]);
    __syncthreads();

    for (int ks = 0; ks < KSTEPS; ks++) {
        if (ks + 2 < KSTEPS) load_stage(fa[ks & 1], (ks + 2) * 32);   // prefetch dist 2
        compute_step(ks % 3, ks * 32);
        if (ks + 1 < KSTEPS) write_stage((ks + 1) % 3, fa[(ks + 1) & 1]);
        __syncthreads();
    }

    // epilogue: C/D layout col=lane&15, row=(lane>>4)*4+reg; zero C pad cols 302/303
    #pragma unroll
    for (int mt = 0; mt < 4; mt++) {
        int row_b = m0 + mt * 16 + q * 4;
        #pragma unroll
        for (int nt = 0; nt < 5; nt++) {
            int col = nbase + nt * 16 + mr;
            if (col > DD + 1) continue;
            #pragma unroll
            for (int r = 0; r < 4; r++) {
                int row = row_b + r;
                if (row >= M) continue;
                float v = acc[mt][nt][r];
                if (col < DD) {
                    C[(size_t)row * GS + col] = v;
                } else if (col == DD) {
                    a_s[row] = v;
                    C[(size_t)row * GS + DD] = 0.f;       // keep pad col zero
                } else {
                    a_d[row] = v;
                    C[(size_t)row * GS + DD + 1] = 0.f;   // keep pad col zero
                }
            }
        }
    }
}

// ---------------------------------------------------------------- tiled SGEMM (final linear)
#define BM 64
#define BN 64
#define BK 16
__global__ __launch_bounds__(256) void k_gemm_nt(const float* __restrict__ A,
                                                 const float* __restrict__ B,
                                                 float* __restrict__ C,
                                                 int M, int N, int K,
                                                 const float* __restrict__ bias) {
    __shared__ float As[BK][BM + 4];
    __shared__ float Bs[BK][BN + 4];
    int m0 = blockIdx.y * BM;
    int n0 = blockIdx.x * BN;
    int tid = threadIdx.x;
    int tr = tid >> 4;
    int tc = tid & 15;
    float acc[4][4] = {};
    for (int k0 = 0; k0 < K; k0 += BK) {
        #pragma unroll
        for (int j = 0; j < 4; j++) {
            int e = tid + 256 * j;
            int r = e >> 4;
            int k = e & 15;
            int gk = k0 + k;
            int gm = m0 + r;
            float va = 0.f;
            if (gm < M && gk < K) va = A[(size_t)gm * K + gk];
            As[k][r] = va;
            int gn = n0 + r;
            float vb = 0.f;
            if (gn < N && gk < K) vb = B[(size_t)gn * K + gk];
            Bs[k][r] = vb;
        }
        __syncthreads();
        #pragma unroll
        for (int k = 0; k < BK; k++) {
            float a[4], b[4];
            #pragma unroll
            for (int i = 0; i < 4; i++) a[i] = As[k][tr * 4 + i];
            #pragma unroll
            for (int j = 0; j < 4; j++) b[j] = Bs[k][tc * 4 + j];
            #pragma unroll
            for (int i = 0; i < 4; i++)
                #pragma unroll
                for (int j = 0; j < 4; j++)
                    acc[i][j] += a[i] * b[j];
        }
        __syncthreads();
    }
    #pragma unroll
    for (int i = 0; i < 4; i++) {
        int gm = m0 + tr * 4 + i;
        if (gm >= M) continue;
        #pragma unroll
        for (int j = 0; j < 4; j++) {
            int gn = n0 + tc * 4 + j;
            if (gn < N) {
                float v = acc[i][j];
                if (bias) v += bias[gn];
                C[(size_t)gm * N + gn] = v;
            }
        }
    }
}

// ---------------------------------------------------------------- qp = query @ attW  (thread/output)
__global__ __launch_bounds__(256) void k_qp(const float* __restrict__ query,
                                            const float* __restrict__ attW,
                                            float* __restrict__ qp) {
    int b = blockIdx.y;
    int d = blockIdx.x * 256 + threadIdx.x;
    if (d >= DD) return;
    const float* qrow = query + (size_t)b * QQ;
    float acc = 0.f;
    #pragma unroll 8
    for (int q = 0; q < QQ; q++) acc += qrow[q] * attW[(size_t)q * DD + d];
    qp[(size_t)b * DD + d] = acc;
}

// ---------------------------------------------------------------- softmax-aggregate (wave / dst node)
// float4 gather: rows of h have zeroed pad cols 302/303 (GEMM epilogue + this kernel's writes).
__global__ __launch_bounds__(256) void k_aggregate(const float* __restrict__ h,
                                                   const float* __restrict__ a_s,
                                                   const float* __restrict__ a_d,
                                                   const int* __restrict__ offs,
                                                   const int* __restrict__ deg,
                                                   const int* __restrict__ esrc,
                                                   const float* __restrict__ bias,
                                                   float* __restrict__ out) {
    int gid = blockIdx.x * blockDim.x + threadIdx.x;
    int n = gid >> 6, lane = gid & 63;
    if (n >= N_NODES) return;
    int beg = offs[n], cnt = deg[n];
    float adn = a_d[n];
    float m = -INFINITY;
    for (int i = lane; i < cnt; i += 64) {
        float e = a_s[esrc[beg + i]] + adn;
        e = (e > 0.f) ? e : NEG_SLOPE * e;
        m = fmaxf(m, e);
    }
    for (int off = 32; off; off >>= 1) m = fmaxf(m, __shfl_xor(m, off));
    float den = 0.f;
    for (int i = lane; i < cnt; i += 64) {
        float e = a_s[esrc[beg + i]] + adn;
        e = (e > 0.f) ? e : NEG_SLOPE * e;
        den += __expf(e - m);
    }
    for (int off = 32; off; off >>= 1) den += __shfl_xor(den, off);
    float inv_den = 1.f / den;

    const int c0 = lane * 4;            // 0..252  (covers cols 0..255)
    const int c1 = 256 + lane * 4;      // lanes 0..11 cover cols 256..303
    const bool has1 = lane < 12;
    float4 A0 = {0.f, 0.f, 0.f, 0.f};
    float4 A1 = {0.f, 0.f, 0.f, 0.f};
    for (int i = 0; i < cnt; i++) {
        int s = esrc[beg + i];
        float e = a_s[s] + adn;
        e = (e > 0.f) ? e : NEG_SLOPE * e;
        float w = __expf(e - m) * inv_den;
        const float* row = h + (size_t)s * GS;
        float4 r0 = *(const float4*)(row + c0);
        A0.x += w * r0.x; A0.y += w * r0.y; A0.z += w * r0.z; A0.w += w * r0.w;
        if (has1) {
            float4 r1 = *(const float4*)(row + c1);
            A1.x += w * r1.x; A1.y += w * r1.y; A1.z += w * r1.z; A1.w += w * r1.w;
        }
    }
    {
        float4 b0 = *(const float4*)(bias + c0);      // c0 <= 252: in-bounds
        float4 o;
        o.x = fmaxf(A0.x + b0.x, 0.f);
        o.y = fmaxf(A0.y + b0.y, 0.f);
        o.z = fmaxf(A0.z + b0.z, 0.f);
        o.w = fmaxf(A0.w + b0.w, 0.f);
        *(float4*)(out + (size_t)n * GS + c0) = o;
    }
    if (lane < 11) {                                  // cols 256..299
        float4 b1 = *(const float4*)(bias + c1);
        float4 o;
        o.x = fmaxf(A1.x + b1.x, 0.f);
        o.y = fmaxf(A1.y + b1.y, 0.f);
        o.z = fmaxf(A1.z + b1.z, 0.f);
        o.w = fmaxf(A1.w + b1.w, 0.f);
        *(float4*)(out + (size_t)n * GS + c1) = o;
    } else if (lane == 11) {                          // cols 300,301 valid; 302,303 -> 0
        float4 o;
        o.x = fmaxf(A1.x + bias[300], 0.f);
        o.y = fmaxf(A1.y + bias[301], 0.f);
        o.z = 0.f;
        o.w = 0.f;
        *(float4*)(out + (size_t)n * GS + 300) = o;
    }
}

// ---------------------------------------------------------------- pooling pieces
// batch is SORTED -> per-graph bounds via binary search (no atomics).
__global__ void k_gbounds(const int* __restrict__ batch, int* goffs, int* gcnt) {
    __shared__ int bound[BB + 1];
    int b = threadIdx.x;
    if (b <= BB) {
        int lo = 0, hi = N_NODES;
        while (lo < hi) {                 // first i with batch[i] >= b
            int mid = (lo + hi) >> 1;
            if (batch[mid] < b) lo = mid + 1; else hi = mid;
        }
        bound[b] = lo;
    }
    __syncthreads();
    if (b < BB) {
        goffs[b] = bound[b];
        gcnt[b]  = bound[b + 1] - bound[b];
    }
}

__global__ void k_scores(const float* __restrict__ h, int ld,
                         const float* __restrict__ qp,
                         const int* __restrict__ batch, float* sarr) {
    int gid = blockIdx.x * blockDim.x + threadIdx.x;
    int n = gid >> 6, lane = gid & 63;
    if (n >= N_NODES) return;
    const float* row = h + (size_t)n * ld;
    const float* q = qp + (size_t)batch[n] * DD;
    float acc = 0.f;
    for (int j = lane; j < DD; j += 64) acc += row[j] * q[j];
    for (int off = 32; off; off >>= 1) acc += __shfl_down(acc, off);
    if (lane == 0) sarr[n] = acc * 0.04082482904638630f;   // 1/sqrt(600)
}

// per-graph softmax stats over sarr
__global__ __launch_bounds__(256) void k_gstats(const float* __restrict__ sarr,
                                                const int* __restrict__ goffs,
                                                const int* __restrict__ gcnt,
                                                float* __restrict__ gm,
                                                float* __restrict__ gdeninv) {
    int b = blockIdx.x;
    int beg = goffs[b], cnt = gcnt[b];
    __shared__ float red[256];
    float m = -INFINITY;
    for (int i = threadIdx.x; i < cnt; i += 256) m = fmaxf(m, sarr[beg + i]);
    red[threadIdx.x] = m;
    __syncthreads();
    for (int d = 128; d; d >>= 1) {
        if (threadIdx.x < d) red[threadIdx.x] = fmaxf(red[threadIdx.x], red[threadIdx.x + d]);
        __syncthreads();
    }
    m = red[0];
    __syncthreads();
    float den = 0.f;
    for (int i = threadIdx.x; i < cnt; i += 256) den += __expf(sarr[beg + i] - m);
    red[threadIdx.x] = den;
    __syncthreads();
    for (int d = 128; d; d >>= 1) {
        if (threadIdx.x < d) red[threadIdx.x] += red[threadIdx.x + d];
        __syncthreads();
    }
    if (threadIdx.x == 0) {
        gm[b] = m;
        gdeninv[b] = (cnt > 0) ? 1.f / red[0] : 0.f;
    }
}

__global__ void k_wn(const float* __restrict__ sarr, const int* __restrict__ batch,
                     const float* __restrict__ gm, const float* __restrict__ gdeninv,
                     float* __restrict__ wn) {
    int n = blockIdx.x * 256 + threadIdx.x;
    if (n >= N_NODES) return;
    int b = batch[n];
    wn[n] = __expf(sarr[n] - gm[b]) * gdeninv[b];
}

__global__ void k_pzero(float* pooled) {
    int i = blockIdx.x * 256 + threadIdx.x;
    if (i < BB * DD) pooled[i] = 0.f;
}

// node-chunk-parallel weighted segment sum (batch sorted; flush at graph boundaries)
__global__ __launch_bounds__(256) void k_poolacc(const float* __restrict__ h, int ld,
                                                 const float* __restrict__ wn,
                                                 const int* __restrict__ batch,
                                                 float* __restrict__ pooled) {
    int c0 = blockIdx.x * PC;
    if (c0 >= N_NODES) return;
    int nmax = N_NODES - c0; if (nmax > PC) nmax = PC;
    __shared__ int   sb[PC];
    __shared__ float sw[PC];
    for (int i = threadIdx.x; i < nmax; i += 256) {
        sb[i] = batch[c0 + i];
        sw[i] = wn[c0 + i];
    }
    __syncthreads();
    int f0 = threadIdx.x, f1 = threadIdx.x + 256;
    float a0 = 0.f, a1 = 0.f;
    int g = sb[0];
    for (int i = 0; i < nmax; i++) {
        int bi = sb[i];
        if (bi != g) {                       // wave-uniform branch
            if (f0 < DD) atomicAdd(&pooled[(size_t)g * DD + f0], a0);
            if (f1 < DD) atomicAdd(&pooled[(size_t)g * DD + f1], a1);
            a0 = 0.f; a1 = 0.f; g = bi;
        }
        float w = sw[i];
        const float* row = h + (size_t)(c0 + i) * ld;
        if (f0 < DD) a0 += w * row[f0];
        if (f1 < DD) a1 += w * row[f1];
    }
    if (f0 < DD) atomicAdd(&pooled[(size_t)g * DD + f0], a0);
    if (f1 < DD) atomicAdd(&pooled[(size_t)g * DD + f1], a1);
}

__global__ void k_prelu(const float* __restrict__ pooled, float* __restrict__ pr) {
    int i = blockIdx.x * 256 + threadIdx.x;
    if (i < BB * DD) pr[i] = fmaxf(pooled[i], 0.f);
}

// ---------------------------------------------------------------- launch
extern "C" void kernel_launch(void* const* d_in, const int* in_sizes, int n_in,
                              void* d_out, int out_size, void* d_ws, size_t ws_size,
                              hipStream_t stream) {
    const float* x        = (const float*)d_in[0];
    const int*   edges    = (const int*)d_in[1];   // [2, E]
    const float* query    = (const float*)d_in[2];
    const int*   batch    = (const int*)d_in[3];
    const float* theta    = (const float*)d_in[4];
    const float* att_src  = (const float*)d_in[5];
    const float* att_dst  = (const float*)d_in[6];
    const float* gat_bias = (const float*)d_in[7];
    const float* attW     = (const float*)d_in[8];
    const float* lin_w    = (const float*)d_in[9];
    const float* lin_b    = (const float*)d_in[10];
    float* out = (float*)d_out;

    char* ws = (char*)d_ws;
    size_t off = 0;
    auto alloc = [&](size_t bytes) -> void* {
        off = (off + 255) & ~(size_t)255;
        void* p = ws + off;
        off += bytes;
        return p;
    };

    float* G    = (float*)alloc((size_t)N_NODES * GS * 4);   // gemm output (padded stride)
    float* P    = (float*)alloc((size_t)N_NODES * GS * 4);   // layer output (padded stride)
    unsigned short* thhi = (unsigned short*)alloc((size_t)KP * KP * 2);
    unsigned short* thlo = (unsigned short*)alloc((size_t)KP * KP * 2);
    float* a_s  = (float*)alloc((size_t)N_NODES * 4);
    float* a_d  = (float*)alloc((size_t)N_NODES * 4);
    float* sarr = (float*)alloc((size_t)N_NODES * 4);
    float* wn   = (float*)alloc((size_t)N_NODES * 4);
    int* deg    = (int*)alloc((size_t)N_NODES * 4);
    int* cursor = (int*)alloc((size_t)N_NODES * 4);
    int* offs   = (int*)alloc((size_t)N_NODES * 4);
    int* esrc   = (int*)alloc((size_t)(N_EDGES + N_NODES) * 4);
    int* partials = (int*)alloc(256 * 4);
    int* gcnt   = (int*)alloc(BB * 4);
    int* goffs  = (int*)alloc(BB * 4);
    float* gm   = (float*)alloc(BB * 4);
    float* gdi  = (float*)alloc(BB * 4);
    float* qp   = (float*)alloc((size_t)BB * DD * 4);
    float* pooled = (float*)alloc((size_t)BB * DD * 4);
    float* pr   = (float*)alloc((size_t)BB * DD * 4);

    const int* e_src = edges;
    const int* e_dst = edges + N_EDGES;

    const int NB_SCAN = (N_NODES + 255) / 256;   // 196

    // ---- CSR build
    k_deg_init<<<NB_SCAN, 256, 0, stream>>>(deg, cursor);
    k_histogram<<<(N_EDGES + 255) / 256, 256, 0, stream>>>(e_dst, deg);
    k_scan_block<<<NB_SCAN, 256, 0, stream>>>(deg, offs, partials);
    k_scan_partials<<<1, 256, 0, stream>>>(partials, NB_SCAN);
    k_scan_add<<<NB_SCAN, 256, 0, stream>>>(offs, partials);
    k_scatter<<<(N_EDGES + N_NODES + 255) / 256, 256, 0, stream>>>(e_src, e_dst, offs, cursor, esrc);

    // ---- theta hi/lo split + attention-vector rows (once; shared across layers)
    k_theta_prep<<<(KP * KP + 255) / 256, 256, 0, stream>>>(theta, thhi, thlo);
    k_attvec<<<(DD + 255) / 256, 256, 0, stream>>>(theta, att_src, att_dst, thhi, thlo);

    // ---- 3 GAT layers
    int mfma_blocks = (N_NODES + 63) / 64;   // 782
    int wave_blocks = (N_NODES + 3) / 4;
    const float* cur = x;
    int cur_ld = DD;
    for (int layer = 0; layer < 3; layer++) {
        k_mfma_gemm<<<mfma_blocks, 256, 0, stream>>>(cur, cur_ld, thhi, thlo, G, a_s, a_d, N_NODES);
        k_aggregate<<<wave_blocks, 256, 0, stream>>>(G, a_s, a_d, offs, deg, esrc, gat_bias, P);
        cur = P;
        cur_ld = GS;
    }

    // ---- attention pooling + classifier
    {
        dim3 g((DD + 255) / 256, BB);
        k_qp<<<g, 256, 0, stream>>>(query, attW, qp);
    }
    k_gbounds<<<1, 256, 0, stream>>>(batch, goffs, gcnt);
    k_scores<<<wave_blocks, 256, 0, stream>>>(P, GS, qp, batch, sarr);
    k_gstats<<<BB, 256, 0, stream>>>(sarr, goffs, gcnt, gm, gdi);
    k_wn<<<NB_SCAN, 256, 0, stream>>>(sarr, batch, gm, gdi, wn);
    k_pzero<<<(BB * DD + 255) / 256, 256, 0, stream>>>(pooled);
    k_poolacc<<<(N_NODES + PC - 1) / PC, 256, 0, stream>>>(P, GS, wn, batch, pooled);
    k_prelu<<<(BB * DD + 255) / 256, 256, 0, stream>>>(pooled, pr);
    {
        dim3 g((CC + BN - 1) / BN, (BB + BM - 1) / BM);
        k_gemm_nt<<<g, 256, 0, stream>>>(pr, lin_w, out, BB, CC, DD, lin_b);
    }
}